// Round 1
// baseline (249.110 us; speedup 1.0000x reference)
//
#include <hip/hip_runtime.h>

// OctreeCrossEntropyLoss on gfx950.
// Level 0: 4096 blocks x 16^3 voxels, 2-class log-softmax NLL, w=16 for gt==0,
//          per-block weighted-mean, summed. Memory-bound: 192 MB read.
// Levels 1..4: need only min/max of gt per coarse block; gt is 0/1 so per-16^3
//          min/max flags (computed in kernel 1) compose hierarchically.

#define W_INSIDE 16.0f

__global__ __launch_bounds__(256) void level0_kernel(
    const int* __restrict__ gt,
    const float* __restrict__ preds,
    unsigned char* __restrict__ flags,
    float* __restrict__ out)
{
    const int n  = blockIdx.x;                 // 0..4095 block id
    const int bi = n >> 8, bj = (n >> 4) & 15, bk = n & 15;
    const int gbase = (bi * 16) * 65536 + (bj * 16) * 256 + (bk * 16);
    const float* __restrict__ p0 = preds + (size_t)n * 8192;   // class 0 plane
    const float* __restrict__ p1 = p0 + 4096;                  // class 1 plane
    const int t = threadIdx.x;

    float wnll = 0.0f, wsum = 0.0f;
    int mn = 1, mx = 0;

    #pragma unroll
    for (int i = 0; i < 4; ++i) {
        const int v4 = t + 256 * i;            // float4 group index 0..1023
        const int x  = v4 >> 6;
        const int y  = (v4 >> 2) & 15;
        const int z4 = (v4 & 3) * 4;
        const int4   g4 = *reinterpret_cast<const int4*>(gt + gbase + x * 65536 + y * 256 + z4);
        const float4 a  = *reinterpret_cast<const float4*>(p0 + 4 * v4);
        const float4 b  = *reinterpret_cast<const float4*>(p1 + 4 * v4);

        const int   gs[4] = {g4.x, g4.y, g4.z, g4.w};
        const float av[4] = {a.x, a.y, a.z, a.w};
        const float bv[4] = {b.x, b.y, b.z, b.w};
        #pragma unroll
        for (int j = 0; j < 4; ++j) {
            const int tg = gs[j];
            mn = min(mn, tg);
            mx = max(mx, tg);
            // nll = logsumexp(p0,p1) - p_tgt = softplus(-(p_tgt - p_other))
            const float d   = tg ? (bv[j] - av[j]) : (av[j] - bv[j]);
            const float nll = fmaxf(-d, 0.0f) + __logf(1.0f + __expf(-fabsf(d)));
            const float w   = tg ? 1.0f : W_INSIDE;
            wnll += w * nll;
            wsum += w;
        }
    }

    // wave (64-lane) shuffle reduction
    #pragma unroll
    for (int off = 32; off > 0; off >>= 1) {
        wnll += __shfl_down(wnll, off, 64);
        wsum += __shfl_down(wsum, off, 64);
        mn = min(mn, __shfl_down(mn, off, 64));
        mx = max(mx, __shfl_down(mx, off, 64));
    }
    __shared__ float s_wnll[4], s_wsum[4];
    __shared__ int   s_mn[4], s_mx[4];
    const int wave = t >> 6;
    if ((t & 63) == 0) { s_wnll[wave] = wnll; s_wsum[wave] = wsum; s_mn[wave] = mn; s_mx[wave] = mx; }
    __syncthreads();
    if (t == 0) {
        float W = 0.0f, S = 0.0f; int MN = 1, MX = 0;
        #pragma unroll
        for (int w = 0; w < 4; ++w) {
            W += s_wnll[w]; S += s_wsum[w];
            MN = min(MN, s_mn[w]); MX = max(MX, s_mx[w]);
        }
        atomicAdd(out, W / S);
        flags[n] = (unsigned char)(MN | (MX << 1));
    }
}

// Levels 1..4: cascade min/max flags. 512 threads, one workgroup.
__global__ __launch_bounds__(512) void levels_kernel(
    const unsigned char* __restrict__ flags,   // 4096 level-0 flags (16^3 grid)
    const float* __restrict__ ps,              // preds_single (585,3)
    float* __restrict__ out)
{
    __shared__ unsigned char s1[512];
    __shared__ unsigned char s2[64];
    __shared__ unsigned char s3[8];
    const int t = threadIdx.x;
    float acc = 0.0f;

    // level 1: nb=8 (512 blocks), children on 16^3 grid
    {
        const int bi = t >> 6, bj = (t >> 3) & 7, bk = t & 7;
        int mn = 1, mx = 0;
        #pragma unroll
        for (int di = 0; di < 2; ++di)
        #pragma unroll
        for (int dj = 0; dj < 2; ++dj)
        #pragma unroll
        for (int dk = 0; dk < 2; ++dk) {
            const unsigned char c = flags[(2*bi+di)*256 + (2*bj+dj)*16 + (2*bk+dk)];
            mn &= (c & 1);
            mx |= ((c >> 1) & 1);
        }
        const int g = (mn == mx) ? mx : 2;
        acc += __logf(ps[(0 + t) * 3 + g]);
        s1[t] = (unsigned char)(mn | (mx << 1));
    }
    __syncthreads();

    // level 2: nb=4 (64 blocks), children on 8^3 grid (s1)
    if (t < 64) {
        const int bi = t >> 4, bj = (t >> 2) & 3, bk = t & 3;
        int mn = 1, mx = 0;
        #pragma unroll
        for (int di = 0; di < 2; ++di)
        #pragma unroll
        for (int dj = 0; dj < 2; ++dj)
        #pragma unroll
        for (int dk = 0; dk < 2; ++dk) {
            const unsigned char c = s1[(2*bi+di)*64 + (2*bj+dj)*8 + (2*bk+dk)];
            mn &= (c & 1);
            mx |= ((c >> 1) & 1);
        }
        const int g = (mn == mx) ? mx : 2;
        acc += __logf(ps[(512 + t) * 3 + g]);
        s2[t] = (unsigned char)(mn | (mx << 1));
    }
    __syncthreads();

    // level 3: nb=2 (8 blocks), children on 4^3 grid (s2)
    if (t < 8) {
        const int bi = t >> 2, bj = (t >> 1) & 1, bk = t & 1;
        int mn = 1, mx = 0;
        #pragma unroll
        for (int di = 0; di < 2; ++di)
        #pragma unroll
        for (int dj = 0; dj < 2; ++dj)
        #pragma unroll
        for (int dk = 0; dk < 2; ++dk) {
            const unsigned char c = s2[(2*bi+di)*16 + (2*bj+dj)*4 + (2*bk+dk)];
            mn &= (c & 1);
            mx |= ((c >> 1) & 1);
        }
        const int g = (mn == mx) ? mx : 2;
        acc += __logf(ps[(576 + t) * 3 + g]);
        s3[t] = (unsigned char)(mn | (mx << 1));
    }
    __syncthreads();

    // level 4: nb=1 (1 block), children = s3[0..7]
    if (t == 0) {
        int mn = 1, mx = 0;
        #pragma unroll
        for (int c8 = 0; c8 < 8; ++c8) {
            mn &= (s3[c8] & 1);
            mx |= ((s3[c8] >> 1) & 1);
        }
        const int g = (mn == mx) ? mx : 2;
        acc += __logf(ps[584 * 3 + g]);
    }

    // reduce acc over 512 threads (8 waves)
    #pragma unroll
    for (int off = 32; off > 0; off >>= 1)
        acc += __shfl_down(acc, off, 64);
    __shared__ float s_acc[8];
    const int wave = t >> 6;
    if ((t & 63) == 0) s_acc[wave] = acc;
    __syncthreads();
    if (t == 0) {
        float S = 0.0f;
        #pragma unroll
        for (int w = 0; w < 8; ++w) S += s_acc[w];
        atomicAdd(out, S);
    }
}

extern "C" void kernel_launch(void* const* d_in, const int* in_sizes, int n_in,
                              void* d_out, int out_size, void* d_ws, size_t ws_size,
                              hipStream_t stream) {
    const int*   gt    = (const int*)d_in[0];      // (1,256,256,256) int32
    const float* preds = (const float*)d_in[1];    // (4096,2,16,16,16) f32
    const float* ps    = (const float*)d_in[2];    // (585,3) f32
    float* out = (float*)d_out;
    unsigned char* flags = (unsigned char*)d_ws;   // 4096 bytes

    hipMemsetAsync(d_out, 0, out_size * sizeof(float), stream);
    level0_kernel<<<4096, 256, 0, stream>>>(gt, preds, flags, out);
    levels_kernel<<<1, 512, 0, stream>>>(flags, ps, out);
}

// Round 2
// 240.238 us; speedup vs baseline: 1.0369x; 1.0369x over previous
//
#include <hip/hip_runtime.h>

// OctreeCrossEntropyLoss on gfx950.
// Level 0: 4096 blocks x 16^3 voxels, 2-class log-softmax NLL, w=16 for gt==0,
//          per-block weighted-mean, summed. Memory-bound: ~192 MB read.
// Levels 1..4: need only min/max of gt per coarse block; gt is 0/1 so per-16^3
//          min/max flags (computed in kernel 1) compose hierarchically.
//
// R1 lesson: VGPR=20 meant the compiler serialized the 12 vector loads per
// thread (load->waitcnt->use chain) -> 1.57 TB/s, latency-bound. Fix: issue
// all 12 loads into independent named vectors BEFORE any compute so they are
// all in flight together (~48 VGPRs of load data).

#define W_INSIDE 16.0f

__global__ __launch_bounds__(256) void level0_kernel(
    const int* __restrict__ gt,
    const float* __restrict__ preds,
    float* __restrict__ loss,                  // 4096 per-block losses (ws)
    unsigned char* __restrict__ flags)         // 4096 per-block min/max flags (ws)
{
    const int n  = blockIdx.x;                 // 0..4095 block id
    const int bi = n >> 8, bj = (n >> 4) & 15, bk = n & 15;
    const int gbase = (bi * 16) * 65536 + (bj * 16) * 256 + (bk * 16);
    const float* __restrict__ p0 = preds + (size_t)n * 8192;   // class 0 plane
    const float* __restrict__ p1 = p0 + 4096;                  // class 1 plane
    const int t = threadIdx.x;

    // ---- issue ALL loads first (12 x 16B, independent) ----
    int4   g0, g1, g2, g3;
    float4 a0, a1, a2, a3;
    float4 b0, b1, b2, b3;
    {
        const int v0 = t, v1 = t + 256, v2 = t + 512, v3 = t + 768;
        #define GADDR(v) (gt + gbase + ((v) >> 6) * 65536 + (((v) >> 2) & 15) * 256 + ((v) & 3) * 4)
        g0 = *reinterpret_cast<const int4*>(GADDR(v0));
        g1 = *reinterpret_cast<const int4*>(GADDR(v1));
        g2 = *reinterpret_cast<const int4*>(GADDR(v2));
        g3 = *reinterpret_cast<const int4*>(GADDR(v3));
        #undef GADDR
        a0 = *reinterpret_cast<const float4*>(p0 + 4 * v0);
        a1 = *reinterpret_cast<const float4*>(p0 + 4 * v1);
        a2 = *reinterpret_cast<const float4*>(p0 + 4 * v2);
        a3 = *reinterpret_cast<const float4*>(p0 + 4 * v3);
        b0 = *reinterpret_cast<const float4*>(p1 + 4 * v0);
        b1 = *reinterpret_cast<const float4*>(p1 + 4 * v1);
        b2 = *reinterpret_cast<const float4*>(p1 + 4 * v2);
        b3 = *reinterpret_cast<const float4*>(p1 + 4 * v3);
    }

    float wnll = 0.0f, wsum = 0.0f;
    int mn = 1, mx = 0;

    #define DO4(G, A, B)                                                        \
    {                                                                           \
        const int   gs[4] = {G.x, G.y, G.z, G.w};                               \
        const float av[4] = {A.x, A.y, A.z, A.w};                               \
        const float bv[4] = {B.x, B.y, B.z, B.w};                               \
        _Pragma("unroll")                                                       \
        for (int j = 0; j < 4; ++j) {                                           \
            const int tg = gs[j];                                               \
            mn = min(mn, tg);                                                   \
            mx = max(mx, tg);                                                   \
            const float d   = tg ? (bv[j] - av[j]) : (av[j] - bv[j]);           \
            const float nll = fmaxf(-d, 0.0f) + __logf(1.0f + __expf(-fabsf(d))); \
            wnll += tg ? nll : W_INSIDE * nll;                                  \
            wsum += tg ? 1.0f : W_INSIDE;                                       \
        }                                                                       \
    }
    DO4(g0, a0, b0)
    DO4(g1, a1, b1)
    DO4(g2, a2, b2)
    DO4(g3, a3, b3)
    #undef DO4

    // wave (64-lane) shuffle reduction
    #pragma unroll
    for (int off = 32; off > 0; off >>= 1) {
        wnll += __shfl_down(wnll, off, 64);
        wsum += __shfl_down(wsum, off, 64);
        mn = min(mn, __shfl_down(mn, off, 64));
        mx = max(mx, __shfl_down(mx, off, 64));
    }
    __shared__ float s_wnll[4], s_wsum[4];
    __shared__ int   s_mn[4], s_mx[4];
    const int wave = t >> 6;
    if ((t & 63) == 0) { s_wnll[wave] = wnll; s_wsum[wave] = wsum; s_mn[wave] = mn; s_mx[wave] = mx; }
    __syncthreads();
    if (t == 0) {
        float W = 0.0f, S = 0.0f; int MN = 1, MX = 0;
        #pragma unroll
        for (int w = 0; w < 4; ++w) {
            W += s_wnll[w]; S += s_wsum[w];
            MN = min(MN, s_mn[w]); MX = max(MX, s_mx[w]);
        }
        loss[n]  = W / S;
        flags[n] = (unsigned char)(MN | (MX << 1));
    }
}

// Levels 1..4 + final reduction. 512 threads, one workgroup, single store.
__global__ __launch_bounds__(512) void levels_kernel(
    const float* __restrict__ loss,            // 4096 level-0 block losses
    const unsigned char* __restrict__ flags,   // 4096 level-0 flags (16^3 grid)
    const float* __restrict__ ps,              // preds_single (585,3)
    float* __restrict__ out)
{
    __shared__ unsigned char s1[512];
    __shared__ unsigned char s2[64];
    __shared__ unsigned char s3[8];
    const int t = threadIdx.x;
    float acc = 0.0f;

    // level-0 loss reduction: 8 floats per thread (2 x float4)
    {
        const float4 l0 = *reinterpret_cast<const float4*>(loss + 8 * t);
        const float4 l1 = *reinterpret_cast<const float4*>(loss + 8 * t + 4);
        acc += (l0.x + l0.y) + (l0.z + l0.w) + (l1.x + l1.y) + (l1.z + l1.w);
    }

    // level 1: nb=8 (512 blocks), children on 16^3 grid
    {
        const int bi = t >> 6, bj = (t >> 3) & 7, bk = t & 7;
        int mn = 1, mx = 0;
        #pragma unroll
        for (int di = 0; di < 2; ++di)
        #pragma unroll
        for (int dj = 0; dj < 2; ++dj)
        #pragma unroll
        for (int dk = 0; dk < 2; ++dk) {
            const unsigned char c = flags[(2*bi+di)*256 + (2*bj+dj)*16 + (2*bk+dk)];
            mn &= (c & 1);
            mx |= ((c >> 1) & 1);
        }
        const int g = (mn == mx) ? mx : 2;
        acc += __logf(ps[(0 + t) * 3 + g]);
        s1[t] = (unsigned char)(mn | (mx << 1));
    }
    __syncthreads();

    // level 2: nb=4 (64 blocks), children on 8^3 grid (s1)
    if (t < 64) {
        const int bi = t >> 4, bj = (t >> 2) & 3, bk = t & 3;
        int mn = 1, mx = 0;
        #pragma unroll
        for (int di = 0; di < 2; ++di)
        #pragma unroll
        for (int dj = 0; dj < 2; ++dj)
        #pragma unroll
        for (int dk = 0; dk < 2; ++dk) {
            const unsigned char c = s1[(2*bi+di)*64 + (2*bj+dj)*8 + (2*bk+dk)];
            mn &= (c & 1);
            mx |= ((c >> 1) & 1);
        }
        const int g = (mn == mx) ? mx : 2;
        acc += __logf(ps[(512 + t) * 3 + g]);
        s2[t] = (unsigned char)(mn | (mx << 1));
    }
    __syncthreads();

    // level 3: nb=2 (8 blocks), children on 4^3 grid (s2)
    if (t < 8) {
        const int bi = t >> 2, bj = (t >> 1) & 1, bk = t & 1;
        int mn = 1, mx = 0;
        #pragma unroll
        for (int di = 0; di < 2; ++di)
        #pragma unroll
        for (int dj = 0; dj < 2; ++dj)
        #pragma unroll
        for (int dk = 0; dk < 2; ++dk) {
            const unsigned char c = s2[(2*bi+di)*16 + (2*bj+dj)*4 + (2*bk+dk)];
            mn &= (c & 1);
            mx |= ((c >> 1) & 1);
        }
        const int g = (mn == mx) ? mx : 2;
        acc += __logf(ps[(576 + t) * 3 + g]);
        s3[t] = (unsigned char)(mn | (mx << 1));
    }
    __syncthreads();

    // level 4: nb=1 (1 block), children = s3[0..7]
    if (t == 0) {
        int mn = 1, mx = 0;
        #pragma unroll
        for (int c8 = 0; c8 < 8; ++c8) {
            mn &= (s3[c8] & 1);
            mx |= ((s3[c8] >> 1) & 1);
        }
        const int g = (mn == mx) ? mx : 2;
        acc += __logf(ps[584 * 3 + g]);
    }

    // reduce acc over 512 threads (8 waves), single plain store
    #pragma unroll
    for (int off = 32; off > 0; off >>= 1)
        acc += __shfl_down(acc, off, 64);
    __shared__ float s_acc[8];
    const int wave = t >> 6;
    if ((t & 63) == 0) s_acc[wave] = acc;
    __syncthreads();
    if (t == 0) {
        float S = 0.0f;
        #pragma unroll
        for (int w = 0; w < 8; ++w) S += s_acc[w];
        out[0] = S;
    }
}

extern "C" void kernel_launch(void* const* d_in, const int* in_sizes, int n_in,
                              void* d_out, int out_size, void* d_ws, size_t ws_size,
                              hipStream_t stream) {
    const int*   gt    = (const int*)d_in[0];      // (1,256,256,256) int32
    const float* preds = (const float*)d_in[1];    // (4096,2,16,16,16) f32
    const float* ps    = (const float*)d_in[2];    // (585,3) f32
    float* out = (float*)d_out;

    float*         loss  = (float*)d_ws;                    // 16 KB
    unsigned char* flags = (unsigned char*)d_ws + 16384;    // 4 KB

    level0_kernel<<<4096, 256, 0, stream>>>(gt, preds, loss, flags);
    levels_kernel<<<1, 512, 0, stream>>>(loss, flags, ps, out);
}

// Round 4
// 229.510 us; speedup vs baseline: 1.0854x; 1.0467x over previous
//
#include <hip/hip_runtime.h>

// OctreeCrossEntropyLoss on gfx950 — three streaming passes.
//
// R2 lesson: the monolithic level-0 kernel was latency-bound (VGPR=32, loads
// serialized by the compiler; 1.6 TB/s with VALUBusy 16% and duration
// invariant to cache state). Also gt's 64B-rows-strided-1KB access wastes
// half of every 128B line.
// R3 lesson: __builtin_nontemporal_load needs builtin clang vectors
// (ext_vector_type), not HIP_vector_type classes.
//
// Structure:
//   A) gt (64 MB) streamed perfectly coalesced -> 2 MB bitmask in block-major
//      layout (ushort per 16-voxel z-row).
//   B) per-octree-block loss: 8 coalesced 16B preds loads issued before a
//      sched_barrier + __syncthreads (drains AFTER all are in flight -> 8 KB
//      of MLP per wave by construction). Mask read from LDS. Block min/max
//      derived from mask bits. Writes per-block loss + flags.
//   C) levels 1..4 cascade + final reduction, one workgroup, single store.

#define W_INSIDE 16.0f

typedef int   vint4   __attribute__((ext_vector_type(4)));
typedef float vfloat4 __attribute__((ext_vector_type(4)));

// ---------- A: pack gt into per-block bitmask ----------
__global__ __launch_bounds__(256) void gt_pack_kernel(
    const int* __restrict__ gt,
    unsigned short* __restrict__ mask)      // 4096 blocks x 256 rows
{
    const int T = blockIdx.x * 256 + threadIdx.x;   // 0..2^20-1, one 16-voxel row
    const vint4* p = reinterpret_cast<const vint4*>(gt) + 4 * (size_t)T;
    const vint4 q0 = __builtin_nontemporal_load(p + 0);
    const vint4 q1 = __builtin_nontemporal_load(p + 1);
    const vint4 q2 = __builtin_nontemporal_load(p + 2);
    const vint4 q3 = __builtin_nontemporal_load(p + 3);

    unsigned m = 0;
    m |= (q0.x & 1)        | ((q0.y & 1) << 1)  | ((q0.z & 1) << 2)  | ((q0.w & 1) << 3);
    m |= ((q1.x & 1) << 4) | ((q1.y & 1) << 5)  | ((q1.z & 1) << 6)  | ((q1.w & 1) << 7);
    m |= ((q2.x & 1) << 8) | ((q2.y & 1) << 9)  | ((q2.z & 1) << 10) | ((q2.w & 1) << 11);
    m |= ((q3.x & 1) << 12)| ((q3.y & 1) << 13) | ((q3.z & 1) << 14) | ((q3.w & 1) << 15);

    const int x = T >> 12, y = (T >> 4) & 255, z16 = T & 15;
    const int n = ((x >> 4) << 8) | ((y >> 4) << 4) | z16;      // octree block id
    mask[n * 256 + (x & 15) * 16 + (y & 15)] = (unsigned short)m;
}

// ---------- B: level-0 weighted NLL per block ----------
__global__ __launch_bounds__(256, 4) void level0_kernel(
    const float* __restrict__ preds,
    const unsigned short* __restrict__ mask,
    float* __restrict__ loss,                  // 4096 per-block losses
    unsigned char* __restrict__ flags)         // 4096 per-block min/max flags
{
    const int n = blockIdx.x;
    const int t = threadIdx.x;
    const vfloat4* __restrict__ p0 = reinterpret_cast<const vfloat4*>(preds + (size_t)n * 8192);
    const vfloat4* __restrict__ p1 = p0 + 1024;

    // issue ALL 8 preds loads first
    const vfloat4 a0 = __builtin_nontemporal_load(p0 + t);
    const vfloat4 a1 = __builtin_nontemporal_load(p0 + t + 256);
    const vfloat4 a2 = __builtin_nontemporal_load(p0 + t + 512);
    const vfloat4 a3 = __builtin_nontemporal_load(p0 + t + 768);
    const vfloat4 b0 = __builtin_nontemporal_load(p1 + t);
    const vfloat4 b1 = __builtin_nontemporal_load(p1 + t + 256);
    const vfloat4 b2 = __builtin_nontemporal_load(p1 + t + 512);
    const vfloat4 b3 = __builtin_nontemporal_load(p1 + t + 768);
    __builtin_amdgcn_sched_barrier(0);   // keep all loads issued before any consume

    // stage this block's 512 B mask into LDS
    __shared__ unsigned short smask[256];
    if (t < 32)
        reinterpret_cast<vint4*>(smask)[t] =
            *(reinterpret_cast<const vint4*>(mask + (size_t)n * 256) + t);
    __syncthreads();   // drains VMEM after all 8 loads are in flight

    float wnll = 0.0f, wsum = 0.0f;
    unsigned andb = 0xFu, orb = 0u;

    #define DO4(V, A, B)                                                          \
    {                                                                             \
        const int x_ = (V) >> 6, y_ = ((V) >> 2) & 15, z4_ = (V) & 3;             \
        const unsigned bits = ((unsigned)smask[x_ * 16 + y_] >> (z4_ * 4)) & 0xFu;\
        andb &= bits; orb |= bits;                                                \
        const float av[4] = {A.x, A.y, A.z, A.w};                                 \
        const float bv[4] = {B.x, B.y, B.z, B.w};                                 \
        _Pragma("unroll")                                                         \
        for (int j = 0; j < 4; ++j) {                                             \
            const int tg = (bits >> j) & 1;                                       \
            const float d   = tg ? (bv[j] - av[j]) : (av[j] - bv[j]);             \
            const float nll = fmaxf(-d, 0.0f) + __logf(1.0f + __expf(-fabsf(d))); \
            wnll += tg ? nll : W_INSIDE * nll;                                    \
            wsum += tg ? 1.0f : W_INSIDE;                                         \
        }                                                                         \
    }
    DO4(t,       a0, b0)
    DO4(t + 256, a1, b1)
    DO4(t + 512, a2, b2)
    DO4(t + 768, a3, b3)
    #undef DO4

    // wave (64-lane) shuffle reduction
    #pragma unroll
    for (int off = 32; off > 0; off >>= 1) {
        wnll += __shfl_down(wnll, off, 64);
        wsum += __shfl_down(wsum, off, 64);
        andb &= (unsigned)__shfl_down((int)andb, off, 64);
        orb  |= (unsigned)__shfl_down((int)orb,  off, 64);
    }
    __shared__ float s_wnll[4], s_wsum[4];
    __shared__ unsigned s_and[4], s_or[4];
    const int wave = t >> 6;
    if ((t & 63) == 0) { s_wnll[wave] = wnll; s_wsum[wave] = wsum; s_and[wave] = andb; s_or[wave] = orb; }
    __syncthreads();
    if (t == 0) {
        float W = 0.0f, S = 0.0f; unsigned A_ = 0xFu, O_ = 0u;
        #pragma unroll
        for (int w = 0; w < 4; ++w) {
            W += s_wnll[w]; S += s_wsum[w];
            A_ &= s_and[w]; O_ |= s_or[w];
        }
        loss[n]  = W / S;
        const int mn = (A_ == 0xFu) ? 1 : 0;
        const int mx = O_ ? 1 : 0;
        flags[n] = (unsigned char)(mn | (mx << 1));
    }
}

// ---------- C: levels 1..4 + final reduction ----------
__global__ __launch_bounds__(512) void levels_kernel(
    const float* __restrict__ loss,
    const unsigned char* __restrict__ flags,
    const float* __restrict__ ps,              // preds_single (585,3)
    float* __restrict__ out)
{
    __shared__ unsigned char s1[512];
    __shared__ unsigned char s2[64];
    __shared__ unsigned char s3[8];
    const int t = threadIdx.x;
    float acc = 0.0f;

    // level-0 loss reduction: 8 floats per thread
    {
        const vfloat4 l0 = *(reinterpret_cast<const vfloat4*>(loss) + 2 * t);
        const vfloat4 l1 = *(reinterpret_cast<const vfloat4*>(loss) + 2 * t + 1);
        acc += (l0.x + l0.y) + (l0.z + l0.w) + (l1.x + l1.y) + (l1.z + l1.w);
    }

    // level 1: nb=8 (512 blocks), children on 16^3 grid
    {
        const int bi = t >> 6, bj = (t >> 3) & 7, bk = t & 7;
        int mn = 1, mx = 0;
        #pragma unroll
        for (int di = 0; di < 2; ++di)
        #pragma unroll
        for (int dj = 0; dj < 2; ++dj)
        #pragma unroll
        for (int dk = 0; dk < 2; ++dk) {
            const unsigned char c = flags[(2*bi+di)*256 + (2*bj+dj)*16 + (2*bk+dk)];
            mn &= (c & 1);
            mx |= ((c >> 1) & 1);
        }
        const int g = (mn == mx) ? mx : 2;
        acc += __logf(ps[(0 + t) * 3 + g]);
        s1[t] = (unsigned char)(mn | (mx << 1));
    }
    __syncthreads();

    // level 2: nb=4 (64 blocks)
    if (t < 64) {
        const int bi = t >> 4, bj = (t >> 2) & 3, bk = t & 3;
        int mn = 1, mx = 0;
        #pragma unroll
        for (int di = 0; di < 2; ++di)
        #pragma unroll
        for (int dj = 0; dj < 2; ++dj)
        #pragma unroll
        for (int dk = 0; dk < 2; ++dk) {
            const unsigned char c = s1[(2*bi+di)*64 + (2*bj+dj)*8 + (2*bk+dk)];
            mn &= (c & 1);
            mx |= ((c >> 1) & 1);
        }
        const int g = (mn == mx) ? mx : 2;
        acc += __logf(ps[(512 + t) * 3 + g]);
        s2[t] = (unsigned char)(mn | (mx << 1));
    }
    __syncthreads();

    // level 3: nb=2 (8 blocks)
    if (t < 8) {
        const int bi = t >> 2, bj = (t >> 1) & 1, bk = t & 1;
        int mn = 1, mx = 0;
        #pragma unroll
        for (int di = 0; di < 2; ++di)
        #pragma unroll
        for (int dj = 0; dj < 2; ++dj)
        #pragma unroll
        for (int dk = 0; dk < 2; ++dk) {
            const unsigned char c = s2[(2*bi+di)*16 + (2*bj+dj)*4 + (2*bk+dk)];
            mn &= (c & 1);
            mx |= ((c >> 1) & 1);
        }
        const int g = (mn == mx) ? mx : 2;
        acc += __logf(ps[(576 + t) * 3 + g]);
        s3[t] = (unsigned char)(mn | (mx << 1));
    }
    __syncthreads();

    // level 4
    if (t == 0) {
        int mn = 1, mx = 0;
        #pragma unroll
        for (int c8 = 0; c8 < 8; ++c8) {
            mn &= (s3[c8] & 1);
            mx |= ((s3[c8] >> 1) & 1);
        }
        const int g = (mn == mx) ? mx : 2;
        acc += __logf(ps[584 * 3 + g]);
    }

    // reduce over 512 threads, single plain store
    #pragma unroll
    for (int off = 32; off > 0; off >>= 1)
        acc += __shfl_down(acc, off, 64);
    __shared__ float s_acc[8];
    const int wave = t >> 6;
    if ((t & 63) == 0) s_acc[wave] = acc;
    __syncthreads();
    if (t == 0) {
        float S = 0.0f;
        #pragma unroll
        for (int w = 0; w < 8; ++w) S += s_acc[w];
        out[0] = S;
    }
}

extern "C" void kernel_launch(void* const* d_in, const int* in_sizes, int n_in,
                              void* d_out, int out_size, void* d_ws, size_t ws_size,
                              hipStream_t stream) {
    const int*   gt    = (const int*)d_in[0];      // (1,256,256,256) int32
    const float* preds = (const float*)d_in[1];    // (4096,2,16,16,16) f32
    const float* ps    = (const float*)d_in[2];    // (585,3) f32
    float* out = (float*)d_out;

    unsigned short* maskbuf = (unsigned short*)d_ws;                 // 2 MB
    float*          loss    = (float*)((char*)d_ws + (1 << 21));     // 16 KB
    unsigned char*  flagbuf = (unsigned char*)d_ws + (1 << 21) + 16384; // 4 KB

    gt_pack_kernel<<<4096, 256, 0, stream>>>(gt, maskbuf);
    level0_kernel<<<4096, 256, 0, stream>>>(preds, maskbuf, loss, flagbuf);
    levels_kernel<<<1, 512, 0, stream>>>(loss, flagbuf, ps, out);
}

// Round 5
// 218.502 us; speedup vs baseline: 1.1401x; 1.0504x over previous
//
#include <hip/hip_runtime.h>

// OctreeCrossEntropyLoss on gfx950 — fused single-pass main kernel + tiny levels kernel.
//
// R4 lesson: harness re-poison of 512MB ws runs at 6.9 TB/s (machine streams fine);
// our gt_pack had 512B-strided 2-byte stores and level0 was a second 130MB pass.
// Fused: WG = (bi,bj,q) handles 4 blocks n = bi*256+bj*16+4q+k.
//   gt slab (16x16x64 voxels, 64KB) read fully coalesced -> 4KB LDS nibble table.
//   preds (4 x 32KB contiguous) ping-pong double-buffered across k with
//   sched_barrier pinning load issue before compute.
//   wsum/min/max all derived from ones-count c1.

#define W_INSIDE 16.0f

typedef int   vint4   __attribute__((ext_vector_type(4)));
typedef float vfloat4 __attribute__((ext_vector_type(4)));

__global__ __launch_bounds__(256, 2) void main_kernel(
    const int* __restrict__ gt,
    const float* __restrict__ preds,
    float* __restrict__ loss,                  // 4096 per-block losses
    unsigned char* __restrict__ flags)         // 4096 per-block min/max flags
{
    const int w = blockIdx.x;                  // 0..1023
    const int t = threadIdx.x;                 // 0..255
    const int bi = w >> 6, bj = (w >> 2) & 15, q = w & 3;
    const int n0 = bi * 256 + bj * 16 + 4 * q; // first of 4 blocks

    // ---- issue 16 coalesced gt int4 loads (whole 64KB slab) ----
    // slab voxel (X,Y,zl): x=16bi+X, y=16bj+Y, z=64q+zl. int4 idx =
    // x*16384 + y*64 + 16q + Z4, thread t covers Y=t>>4, Z4=t&15, X=i.
    const vint4* __restrict__ gt4 = reinterpret_cast<const vint4*>(gt);
    const int gbase = bi * 262144 + bj * 1024 + (t >> 4) * 64 + 16 * q + (t & 15);
    vint4 G[16];
    #pragma unroll
    for (int i = 0; i < 16; ++i)
        G[i] = __builtin_nontemporal_load(gt4 + gbase + i * 16384);

    // ---- issue preds loads for block k=0 (8 x 16B, coalesced) ----
    const vfloat4* __restrict__ pb = reinterpret_cast<const vfloat4*>(preds) + (size_t)n0 * 2048;
    vfloat4 A[8], B[8];
    #define LOAD8(DST, kk)                                                         \
    {                                                                              \
        _Pragma("unroll")                                                          \
        for (int j = 0; j < 4; ++j) {                                              \
            DST[j]     = __builtin_nontemporal_load(pb + (kk) * 2048 + t + 256 * j);          \
            DST[4 + j] = __builtin_nontemporal_load(pb + (kk) * 2048 + 1024 + t + 256 * j);   \
        }                                                                          \
    }
    LOAD8(A, 0)
    __builtin_amdgcn_sched_barrier(0);

    // ---- pack gt bits into LDS nibble table: nib[X*256 + Y*16 + Z4] ----
    __shared__ unsigned char nib[4096];
    #pragma unroll
    for (int i = 0; i < 16; ++i) {
        const unsigned m = (G[i].x & 1) | ((G[i].y & 1) << 1)
                         | ((G[i].z & 1) << 2) | ((G[i].w & 1) << 3);
        nib[i * 256 + t] = (unsigned char)m;
    }
    __syncthreads();

    float wnll[4];
    int   c1[4];

    // per-block compute: voxel group g = t+256j covers x=g>>6, y=(g>>2)&15,
    // z = (g&3)*4 + j2 within block k; its nibble is nib[(g>>6)*256 +
    // ((g>>2)&15)*16 + k*4 + (g&3)].
    #define COMP(SRC, kk)                                                          \
    {                                                                              \
        float wn = 0.0f; int cc = 0;                                               \
        _Pragma("unroll")                                                          \
        for (int j = 0; j < 4; ++j) {                                              \
            const int g = t + 256 * j;                                             \
            const unsigned bits =                                                  \
                nib[(g >> 6) * 256 + ((g >> 2) & 15) * 16 + (kk) * 4 + (g & 3)];   \
            cc += __builtin_popcount(bits);                                        \
            const float av[4] = {SRC[j].x, SRC[j].y, SRC[j].z, SRC[j].w};          \
            const float bv[4] = {SRC[4+j].x, SRC[4+j].y, SRC[4+j].z, SRC[4+j].w};  \
            _Pragma("unroll")                                                      \
            for (int j2 = 0; j2 < 4; ++j2) {                                       \
                const int tg = (bits >> j2) & 1;                                   \
                const float d   = tg ? (bv[j2] - av[j2]) : (av[j2] - bv[j2]);      \
                const float nll = fmaxf(-d, 0.0f) + __logf(1.0f + __expf(-fabsf(d))); \
                wn += tg ? nll : W_INSIDE * nll;                                   \
            }                                                                      \
        }                                                                          \
        wnll[kk] = wn; c1[kk] = cc;                                                \
    }

    LOAD8(B, 1) __builtin_amdgcn_sched_barrier(0); COMP(A, 0)
    LOAD8(A, 2) __builtin_amdgcn_sched_barrier(0); COMP(B, 1)
    LOAD8(B, 3) __builtin_amdgcn_sched_barrier(0); COMP(A, 2)
    COMP(B, 3)
    #undef LOAD8
    #undef COMP

    // ---- reductions: 2 quantities x 4 blocks ----
    __shared__ float s_w[4][4];
    __shared__ int   s_c[4][4];
    const int wave = t >> 6;
    #pragma unroll
    for (int k = 0; k < 4; ++k) {
        float wv = wnll[k];
        int   cv = c1[k];
        #pragma unroll
        for (int off = 32; off > 0; off >>= 1) {
            wv += __shfl_down(wv, off, 64);
            cv += __shfl_down(cv, off, 64);
        }
        if ((t & 63) == 0) { s_w[k][wave] = wv; s_c[k][wave] = cv; }
    }
    __syncthreads();
    if (t < 4) {
        const float W = (s_w[t][0] + s_w[t][1]) + (s_w[t][2] + s_w[t][3]);
        const int   C = (s_c[t][0] + s_c[t][1]) + (s_c[t][2] + s_c[t][3]);
        loss[n0 + t]  = W / (65536.0f - 15.0f * (float)C);
        flags[n0 + t] = (unsigned char)((C == 4096 ? 1 : 0) | (C > 0 ? 2 : 0));
    }
}

// ---------- levels 1..4 + final reduction (unchanged from R4, passed) ----------
__global__ __launch_bounds__(512) void levels_kernel(
    const float* __restrict__ loss,
    const unsigned char* __restrict__ flags,
    const float* __restrict__ ps,              // preds_single (585,3)
    float* __restrict__ out)
{
    __shared__ unsigned char s1[512];
    __shared__ unsigned char s2[64];
    __shared__ unsigned char s3[8];
    const int t = threadIdx.x;
    float acc = 0.0f;

    // level-0 loss reduction: 8 floats per thread
    {
        const vfloat4 l0 = *(reinterpret_cast<const vfloat4*>(loss) + 2 * t);
        const vfloat4 l1 = *(reinterpret_cast<const vfloat4*>(loss) + 2 * t + 1);
        acc += (l0.x + l0.y) + (l0.z + l0.w) + (l1.x + l1.y) + (l1.z + l1.w);
    }

    // level 1: nb=8 (512 blocks), children on 16^3 grid
    {
        const int bi = t >> 6, bj = (t >> 3) & 7, bk = t & 7;
        int mn = 1, mx = 0;
        #pragma unroll
        for (int di = 0; di < 2; ++di)
        #pragma unroll
        for (int dj = 0; dj < 2; ++dj)
        #pragma unroll
        for (int dk = 0; dk < 2; ++dk) {
            const unsigned char c = flags[(2*bi+di)*256 + (2*bj+dj)*16 + (2*bk+dk)];
            mn &= (c & 1);
            mx |= ((c >> 1) & 1);
        }
        const int g = (mn == mx) ? mx : 2;
        acc += __logf(ps[(0 + t) * 3 + g]);
        s1[t] = (unsigned char)(mn | (mx << 1));
    }
    __syncthreads();

    // level 2: nb=4 (64 blocks)
    if (t < 64) {
        const int bi = t >> 4, bj = (t >> 2) & 3, bk = t & 3;
        int mn = 1, mx = 0;
        #pragma unroll
        for (int di = 0; di < 2; ++di)
        #pragma unroll
        for (int dj = 0; dj < 2; ++dj)
        #pragma unroll
        for (int dk = 0; dk < 2; ++dk) {
            const unsigned char c = s1[(2*bi+di)*64 + (2*bj+dj)*8 + (2*bk+dk)];
            mn &= (c & 1);
            mx |= ((c >> 1) & 1);
        }
        const int g = (mn == mx) ? mx : 2;
        acc += __logf(ps[(512 + t) * 3 + g]);
        s2[t] = (unsigned char)(mn | (mx << 1));
    }
    __syncthreads();

    // level 3: nb=2 (8 blocks)
    if (t < 8) {
        const int bi = t >> 2, bj = (t >> 1) & 1, bk = t & 1;
        int mn = 1, mx = 0;
        #pragma unroll
        for (int di = 0; di < 2; ++di)
        #pragma unroll
        for (int dj = 0; dj < 2; ++dj)
        #pragma unroll
        for (int dk = 0; dk < 2; ++dk) {
            const unsigned char c = s2[(2*bi+di)*16 + (2*bj+dj)*4 + (2*bk+dk)];
            mn &= (c & 1);
            mx |= ((c >> 1) & 1);
        }
        const int g = (mn == mx) ? mx : 2;
        acc += __logf(ps[(576 + t) * 3 + g]);
        s3[t] = (unsigned char)(mn | (mx << 1));
    }
    __syncthreads();

    // level 4
    if (t == 0) {
        int mn = 1, mx = 0;
        #pragma unroll
        for (int c8 = 0; c8 < 8; ++c8) {
            mn &= (s3[c8] & 1);
            mx |= ((s3[c8] >> 1) & 1);
        }
        const int g = (mn == mx) ? mx : 2;
        acc += __logf(ps[584 * 3 + g]);
    }

    // reduce over 512 threads, single plain store
    #pragma unroll
    for (int off = 32; off > 0; off >>= 1)
        acc += __shfl_down(acc, off, 64);
    __shared__ float s_acc[8];
    const int wave = t >> 6;
    if ((t & 63) == 0) s_acc[wave] = acc;
    __syncthreads();
    if (t == 0) {
        float S = 0.0f;
        #pragma unroll
        for (int w8 = 0; w8 < 8; ++w8) S += s_acc[w8];
        out[0] = S;
    }
}

extern "C" void kernel_launch(void* const* d_in, const int* in_sizes, int n_in,
                              void* d_out, int out_size, void* d_ws, size_t ws_size,
                              hipStream_t stream) {
    const int*   gt    = (const int*)d_in[0];      // (1,256,256,256) int32
    const float* preds = (const float*)d_in[1];    // (4096,2,16,16,16) f32
    const float* ps    = (const float*)d_in[2];    // (585,3) f32
    float* out = (float*)d_out;

    float*         loss    = (float*)d_ws;                  // 16 KB
    unsigned char* flagbuf = (unsigned char*)d_ws + 16384;  // 4 KB

    main_kernel<<<1024, 256, 0, stream>>>(gt, preds, loss, flagbuf);
    levels_kernel<<<1, 512, 0, stream>>>(loss, flagbuf, ps, out);
}